// Round 2
// baseline (389.155 us; speedup 1.0000x reference)
//
#include <hip/hip_runtime.h>
#include <hip/hip_bf16.h>

// y = (fq_per_token(x) @ fq_per_channel(w)^T) + b
// Exact int8 factorization: y[m,n] = sx[m]*sw[n]*dot_i32(qx[m,:],qw[n,:]) + b[n]

#define K_DIM 4096
#define N_DIM 4096
#define NT (K_DIM / 128)   // 32 K-tiles of 128 bytes

typedef int v4i __attribute__((ext_vector_type(4)));

__device__ __forceinline__ void cp16(void* lds, const void* g) {
    __builtin_amdgcn_global_load_lds(
        (const __attribute__((address_space(1))) void*)g,
        (__attribute__((address_space(3))) void*)lds, 16, 0, 0);
}

// ---------------------------------------------------------------------------
// Per-row symmetric int8 fake-quant, x and w merged into one grid. UNCHANGED.
// ---------------------------------------------------------------------------
__global__ __launch_bounds__(256) void quant_rows_kernel(
    const float* __restrict__ x, const float* __restrict__ w, int M,
    char* __restrict__ qx, char* __restrict__ qw,
    float* __restrict__ sx, float* __restrict__ sw) {
    const int blk = blockIdx.x;
    const bool is_x = blk < M;
    const int row = is_x ? blk : blk - M;
    const float* rp = (is_x ? x : w) + (size_t)row * 4096;
    char* qdst = is_x ? qx : qw;
    float* sdst = is_x ? sx : sw;

    const int tid = threadIdx.x;

    float4 v[4];
#pragma unroll
    for (int i = 0; i < 4; ++i)
        v[i] = *(const float4*)(rp + 4 * (tid + 256 * i));

    float m = 0.0f;
#pragma unroll
    for (int i = 0; i < 4; ++i) {
        m = fmaxf(m, fmaxf(fmaxf(fabsf(v[i].x), fabsf(v[i].y)),
                           fmaxf(fabsf(v[i].z), fabsf(v[i].w))));
    }
#pragma unroll
    for (int off = 32; off > 0; off >>= 1)
        m = fmaxf(m, __shfl_down(m, off));

    __shared__ float red[4];
    if ((tid & 63) == 0) red[tid >> 6] = m;
    __syncthreads();
    const float amax = fmaxf(fmaxf(red[0], red[1]), fmaxf(red[2], red[3]));
    const float scale = fmaxf(amax / 127.0f, 1e-8f);

    int* qout = (int*)(qdst + (size_t)row * 4096);
#pragma unroll
    for (int i = 0; i < 4; ++i) {
        int q0 = (int)fminf(fmaxf(rintf(v[i].x / scale), -128.0f), 127.0f);
        int q1 = (int)fminf(fmaxf(rintf(v[i].y / scale), -128.0f), 127.0f);
        int q2 = (int)fminf(fmaxf(rintf(v[i].z / scale), -128.0f), 127.0f);
        int q3 = (int)fminf(fmaxf(rintf(v[i].w / scale), -128.0f), 127.0f);
        qout[tid + 256 * i] =
            (q0 & 255) | ((q1 & 255) << 8) | ((q2 & 255) << 16) | ((q3 & 255) << 24);
    }
    if (tid == 0) sdst[row] = scale;
}

// ---------------------------------------------------------------------------
// int8 GEMM, 256x256 tile, 8 waves (2M x 4N), BK = 128 bytes, 4-phase K-tile.
//
// Round-2 change: register-double-buffered fragments. Each phase ISSUES the
// ds_reads for the NEXT phase's fragments (no wait) and CONSUMES fragments
// issued one phase earlier -> LDS read window hides under the 16-MFMA
// cluster instead of serializing with it (round-1: 5198 cy/K-tile measured
// vs 2611 cy MFMA floor; the gap was the serialized ds window).
//
// Fragment schedule (tile t, parity par; aA/aB and b0/b1 reg ping-pong):
//   P1: issue A(t) ch0 m4-7 -> aB ; stage B(t+1)       ; MFMA(aA,b0)->acc[0-3]
//   P2: issue A(t) ch1 m0-3 -> aA , B(t) ch1 -> b1     ; MFMA(aB,b0)->acc[4-7]
//   P3: issue A(t) ch1 m4-7 -> aB                      ; MFMA(aA,b1)->acc[0-3]
//       then lgkmcnt(0) (cross-wave WAR fence) + vmcnt(0) (A(t+1),B(t+1)
//       landed) before the trailing barrier
//   P4: issue A(t+1) ch0 m0-3 -> aA , B(t+1) ch0 -> b0 ; MFMA(aB,b1)->acc[4-7]
//       then stage A(t+2) (slot A(t) provably retired: its last reads were
//       consumed by this phase's MFMA)
//
// vmcnt(0) at end-P3 drains ONLY loads needed by the very next phase
// (A(t+1): issued 3 phases prior; B(t+1): 2 phases prior) — counted-
// pipeline depth is preserved, no useful load is drained early.
//
// LDS swizzle unchanged (0 conflicts measured): chunk c of row r stored at
// c ^ (r&7); read chunk = (ks*4+lg) ^ (ln&7).
// ---------------------------------------------------------------------------
__global__ __launch_bounds__(512, 2) void gemm_i8_kernel(
    const char* __restrict__ qx, const char* __restrict__ qw,
    const float* __restrict__ sx, const float* __restrict__ sw,
    const float* __restrict__ bias, float* __restrict__ y) {

    __shared__ __align__(16) char lds[131072];

    const int tid  = threadIdx.x;
    const int wave = tid >> 6;
    const int lane = tid & 63;
    const int ln   = lane & 15;   // MFMA column index
    const int lg   = lane >> 4;   // MFMA lane-group 0..3
    const int wm   = wave >> 2;   // wave tile m (0..1) -> rows wm*128..+127
    const int wn   = wave & 3;    // wave tile n (0..3) -> cols wn*64..+63

    const int bm = blockIdx.y;
    const int bn = blockIdx.x;

    const int ci0 = tid,       r0s = ci0 >> 3, c0s = (ci0 & 7) ^ (r0s & 7);
    const int ci1 = tid + 512, r1s = ci1 >> 3, c1s = (ci1 & 7) ^ (r1s & 7);
    const char* aS0 = qx + (size_t)(bm * 256 + r0s) * K_DIM + c0s * 16;
    const char* aS1 = qx + (size_t)(bm * 256 + r1s) * K_DIM + c1s * 16;
    const char* bS0 = qw + (size_t)(bn * 256 + r0s) * K_DIM + c0s * 16;
    const char* bS1 = qw + (size_t)(bn * 256 + r1s) * K_DIM + c1s * 16;
    const int ldsC0 = ci0 * 16, ldsC1 = ci1 * 16;

#define SLOT_A(par, h) ((par) * 65536 + (h) * 16384)
#define SLOT_B(par, h) ((par) * 65536 + 32768 + (h) * 16384)
#define STAGE_A(par, h, t) do {                                              \
    cp16(lds + SLOT_A(par, h) + ldsC0,                                       \
         aS0 + (size_t)(h) * 128 * K_DIM + (size_t)(t) * 128);               \
    cp16(lds + SLOT_A(par, h) + ldsC1,                                       \
         aS1 + (size_t)(h) * 128 * K_DIM + (size_t)(t) * 128); } while (0)
#define STAGE_B(par, h, t) do {                                              \
    cp16(lds + SLOT_B(par, h) + ldsC0,                                       \
         bS0 + (size_t)(h) * 128 * K_DIM + (size_t)(t) * 128);               \
    cp16(lds + SLOT_B(par, h) + ldsC1,                                       \
         bS1 + (size_t)(h) * 128 * K_DIM + (size_t)(t) * 128); } while (0)

#define BAR()  __builtin_amdgcn_s_barrier()
#define FENCE() asm volatile("" ::: "memory")
#define SCHED() __builtin_amdgcn_sched_barrier(0)

    // fragment read offsets (within parity)
    const int ch0 = (lg ^ (ln & 7)) * 16;   // kstep 0 swizzled chunk
    const int ch1 = ch0 ^ 64;               // kstep 1 (chunk index ^ 4)
    const int aRd = wm * 16384 + ln * 128;                        // + m*2048
    const int bRd = 32768 + (wn >> 1) * 16384 + ((wn & 1) * 64 + ln) * 128;

    v4i acc[8][4] = {};
    v4i aA[4], aB[4], b0[4], b1[4];

    // ---- prologue: stage A(0),B(0),A(1); drain A(0),B(0); preload P1 frags
    STAGE_A(0, 0, 0); STAGE_A(0, 1, 0);
    STAGE_B(0, 0, 0); STAGE_B(0, 1, 0);
    STAGE_A(1, 0, 1); STAGE_A(1, 1, 1);
    asm volatile("s_waitcnt vmcnt(4)" ::: "memory");   // A(1) stays in flight
    BAR(); FENCE();
#pragma unroll
    for (int m = 0; m < 4; ++m)
        aA[m] = *(const v4i*)(lds + aRd + m * 2048 + ch0);
#pragma unroll
    for (int n = 0; n < 4; ++n)
        b0[n] = *(const v4i*)(lds + bRd + n * 2048 + ch0);

    for (int t = 0; t < NT; ++t) {
        const int par   = t & 1;
        const int base  = par << 16;
        const int baseN = base ^ 65536;

        // ===== P1: issue aB (A ch0 m4-7), stage B(t+1); MFMA(aA,b0) ========
#pragma unroll
        for (int m = 0; m < 4; ++m)
            aB[m] = *(const v4i*)(lds + base + aRd + (4 + m) * 2048 + ch0);
        if (t + 1 < NT) { STAGE_B(par ^ 1, 0, t + 1); STAGE_B(par ^ 1, 1, t + 1); }
        SCHED();
        BAR(); FENCE();
        SCHED();
        __builtin_amdgcn_s_setprio(1);
#pragma unroll
        for (int m = 0; m < 4; ++m)
#pragma unroll
            for (int n = 0; n < 4; ++n)
                acc[m][n] = __builtin_amdgcn_mfma_i32_16x16x64_i8(
                    aA[m], b0[n], acc[m][n], 0, 0, 0);
        __builtin_amdgcn_s_setprio(0);
        BAR(); FENCE();

        // ===== P2: issue aA (A ch1 m0-3) + b1 (B ch1); MFMA(aB,b0) =========
#pragma unroll
        for (int m = 0; m < 4; ++m)
            aA[m] = *(const v4i*)(lds + base + aRd + m * 2048 + ch1);
#pragma unroll
        for (int n = 0; n < 4; ++n)
            b1[n] = *(const v4i*)(lds + base + bRd + n * 2048 + ch1);
        SCHED();
        BAR(); FENCE();
        SCHED();
        __builtin_amdgcn_s_setprio(1);
#pragma unroll
        for (int m = 0; m < 4; ++m)
#pragma unroll
            for (int n = 0; n < 4; ++n)
                acc[4 + m][n] = __builtin_amdgcn_mfma_i32_16x16x64_i8(
                    aB[m], b0[n], acc[4 + m][n], 0, 0, 0);
        __builtin_amdgcn_s_setprio(0);
        BAR(); FENCE();

        // ===== P3: issue aB (A ch1 m4-7); MFMA(aA,b1); lgkm0+vmcnt0 ========
#pragma unroll
        for (int m = 0; m < 4; ++m)
            aB[m] = *(const v4i*)(lds + base + aRd + (4 + m) * 2048 + ch1);
        SCHED();
        BAR(); FENCE();
        SCHED();
        __builtin_amdgcn_s_setprio(1);
#pragma unroll
        for (int m = 0; m < 4; ++m)
#pragma unroll
            for (int n = 0; n < 4; ++n)
                acc[m][n] = __builtin_amdgcn_mfma_i32_16x16x64_i8(
                    aA[m], b1[n], acc[m][n], 0, 0, 0);
        __builtin_amdgcn_s_setprio(0);
        // own P3 frag reads done (cross-wave WAR fence for stages after the
        // barrier) + own stages for tile t+1 landed:
        asm volatile("s_waitcnt lgkmcnt(0)" ::: "memory");
        asm volatile("s_waitcnt vmcnt(0)" ::: "memory");
        BAR(); FENCE();

        // ===== P4: issue aA (A(t+1) ch0 m0-3) + b0 (B(t+1) ch0);
        //           MFMA(aB,b1); stage A(t+2) ===============================
        if (t + 1 < NT) {
#pragma unroll
            for (int m = 0; m < 4; ++m)
                aA[m] = *(const v4i*)(lds + baseN + aRd + m * 2048 + ch0);
#pragma unroll
            for (int n = 0; n < 4; ++n)
                b0[n] = *(const v4i*)(lds + baseN + bRd + n * 2048 + ch0);
        }
        SCHED();
        BAR(); FENCE();
        SCHED();
        __builtin_amdgcn_s_setprio(1);
#pragma unroll
        for (int m = 0; m < 4; ++m)
#pragma unroll
            for (int n = 0; n < 4; ++n)
                acc[4 + m][n] = __builtin_amdgcn_mfma_i32_16x16x64_i8(
                    aB[m], b1[n], acc[4 + m][n], 0, 0, 0);
        __builtin_amdgcn_s_setprio(0);
        // A(t) slots provably retired (their last reads fed this cluster):
        if (t + 2 < NT) { STAGE_A(par, 0, t + 2); STAGE_A(par, 1, t + 2); }
        SCHED();
        BAR(); FENCE();
    }

    // ---- epilogue. C/D (16x16): col = lane&15, row = (lane>>4)*4 + reg.
    const int m_base = bm * 256 + wm * 128;
    const int n_base = bn * 256 + wn * 64;

    float sxr[8][4];
#pragma unroll
    for (int m = 0; m < 8; ++m)
#pragma unroll
        for (int r = 0; r < 4; ++r)
            sxr[m][r] = sx[m_base + m * 16 + lg * 4 + r];

#pragma unroll
    for (int n = 0; n < 4; ++n) {
        const int col = n_base + n * 16 + ln;
        const float swv = sw[col];
        const float bv  = bias[col];
#pragma unroll
        for (int m = 0; m < 8; ++m) {
            const int row = m_base + m * 16 + lg * 4;
#pragma unroll
            for (int r = 0; r < 4; ++r) {
                y[(size_t)(row + r) * N_DIM + col] =
                    (float)acc[m][n][r] * sxr[m][r] * swv + bv;
            }
        }
    }
#undef SLOT_A
#undef SLOT_B
#undef STAGE_A
#undef STAGE_B
#undef BAR
#undef FENCE
#undef SCHED
}

extern "C" void kernel_launch(void* const* d_in, const int* in_sizes, int n_in,
                              void* d_out, int out_size, void* d_ws, size_t ws_size,
                              hipStream_t stream) {
    const float* x = (const float*)d_in[0];   // [B*S, 4096] = [8192, 4096]
    const float* w = (const float*)d_in[1];   // [4096, 4096]
    const float* b = (const float*)d_in[2];   // [4096]
    float* y = (float*)d_out;                 // [8192, 4096]

    const int M = in_sizes[0] / K_DIM;        // 8192
    const int O = in_sizes[1] / K_DIM;        // 4096

    // Workspace layout
    char* qx = (char*)d_ws;                           // M*4096 int8
    char* qw = qx + (size_t)M * K_DIM;                // O*4096 int8
    float* sx = (float*)(qw + (size_t)O * K_DIM);     // M floats
    float* sw = sx + M;                               // O floats

    quant_rows_kernel<<<M + O, 256, 0, stream>>>(x, w, M, qx, qw, sx, sw);

    dim3 grid(N_DIM / 256, M / 256);                  // (16, 32) = 512 blocks
    gemm_i8_kernel<<<grid, 512, 0, stream>>>(qx, qw, sx, sw, b, y);
}

// Round 4
// 384.529 us; speedup vs baseline: 1.0120x; 1.0120x over previous
//
#include <hip/hip_runtime.h>
#include <hip/hip_bf16.h>

// y = (fq_per_token(x) @ fq_per_channel(w)^T) + b
// Exact int8 factorization: y[m,n] = sx[m]*sw[n]*dot_i32(qx[m,:],qw[n,:]) + b[n]

#define K_DIM 4096
#define N_DIM 4096
#define NT (K_DIM / 128)   // 32 K-tiles of 128 bytes

typedef int v4i __attribute__((ext_vector_type(4)));

__device__ __forceinline__ void cp16(void* lds, const void* g) {
    __builtin_amdgcn_global_load_lds(
        (const __attribute__((address_space(1))) void*)g,
        (__attribute__((address_space(3))) void*)lds, 16, 0, 0);
}

// ---------------------------------------------------------------------------
// Per-row symmetric int8 fake-quant, x and w merged into one grid. UNCHANGED.
// ---------------------------------------------------------------------------
__global__ __launch_bounds__(256) void quant_rows_kernel(
    const float* __restrict__ x, const float* __restrict__ w, int M,
    char* __restrict__ qx, char* __restrict__ qw,
    float* __restrict__ sx, float* __restrict__ sw) {
    const int blk = blockIdx.x;
    const bool is_x = blk < M;
    const int row = is_x ? blk : blk - M;
    const float* rp = (is_x ? x : w) + (size_t)row * 4096;
    char* qdst = is_x ? qx : qw;
    float* sdst = is_x ? sx : sw;

    const int tid = threadIdx.x;

    float4 v[4];
#pragma unroll
    for (int i = 0; i < 4; ++i)
        v[i] = *(const float4*)(rp + 4 * (tid + 256 * i));

    float m = 0.0f;
#pragma unroll
    for (int i = 0; i < 4; ++i) {
        m = fmaxf(m, fmaxf(fmaxf(fabsf(v[i].x), fabsf(v[i].y)),
                           fmaxf(fabsf(v[i].z), fabsf(v[i].w))));
    }
#pragma unroll
    for (int off = 32; off > 0; off >>= 1)
        m = fmaxf(m, __shfl_down(m, off));

    __shared__ float red[4];
    if ((tid & 63) == 0) red[tid >> 6] = m;
    __syncthreads();
    const float amax = fmaxf(fmaxf(red[0], red[1]), fmaxf(red[2], red[3]));
    const float scale = fmaxf(amax / 127.0f, 1e-8f);

    int* qout = (int*)(qdst + (size_t)row * 4096);
#pragma unroll
    for (int i = 0; i < 4; ++i) {
        int q0 = (int)fminf(fmaxf(rintf(v[i].x / scale), -128.0f), 127.0f);
        int q1 = (int)fminf(fmaxf(rintf(v[i].y / scale), -128.0f), 127.0f);
        int q2 = (int)fminf(fmaxf(rintf(v[i].z / scale), -128.0f), 127.0f);
        int q3 = (int)fminf(fmaxf(rintf(v[i].w / scale), -128.0f), 127.0f);
        qout[tid + 256 * i] =
            (q0 & 255) | ((q1 & 255) << 8) | ((q2 & 255) << 16) | ((q3 & 255) << 24);
    }
    if (tid == 0) sdst[row] = scale;
}

// ---------------------------------------------------------------------------
// int8 GEMM, 256x256 tile, 8 waves (2M x 4N), BK = 128 bytes, 2-PHASE K-tile.
// ONLY change vs the round-2 (138.6us, MfmaUtil 42%) kernel: phase count.
//
// Round-2 evidence: ~5300 cy/K-tile measured vs 2611 cy MFMA floor, bank
// conflicts 0, HBM 26% -> gap is ~650 cy overhead per barrier-phase (8-wave
// barrier skew + post-barrier LDS latency), paid 4x/tile. This round: 2
// phases/tile, each = {12 ds_read_b128 (one full k-step of fragments) ||
// one stage burst} -> barrier -> 32 MFMA -> barrier. MFMA window per SIMD
// grows 653 -> 1306 cy; the 96 b128 reads/phase (~1150 cy CU-wide) now fit
// underneath it; barrier overhead paid 4x -> 2x... per-tile predict ~3900cy.
//
// Staging (proven): A(t+1) issued in P1, B(t+1) in P2, single vmcnt(0) at
// end-P2. At the drain, in-flight loads are A(t+1) (1 phase + MFMA window
// old) and B(t+1) (covered by P2's 1306 cy MFMA window > HBM ~900 cy).
// WAR safety: slot par^1 was last ds_read in tile t-1 P2; those reads were
// consumed by t-1 P2's MFMAs, hence complete before t-1's trailing barrier,
// which precedes these stage-writes.
//
// LDS swizzle (proven, 0 conflicts): 16B chunk c of row r stored at
// c ^ (r&7); fragment read chunk = (ks*4 + lg) ^ (ln&7).
// ---------------------------------------------------------------------------
__global__ __launch_bounds__(512, 2) void gemm_i8_kernel(
    const char* __restrict__ qx, const char* __restrict__ qw,
    const float* __restrict__ sx, const float* __restrict__ sw,
    const float* __restrict__ bias, float* __restrict__ y) {

    __shared__ __align__(16) char lds[131072];

    const int tid  = threadIdx.x;
    const int wave = tid >> 6;
    const int lane = tid & 63;
    const int ln   = lane & 15;   // MFMA column index
    const int lg   = lane >> 4;   // MFMA lane-group 0..3
    const int wm   = wave >> 2;   // wave tile m (0..1) -> rows wm*128..+127
    const int wn   = wave & 3;    // wave tile n (0..3) -> cols wn*64..+63

    const int bm = blockIdx.y;
    const int bn = blockIdx.x;

    // staging: thread t handles 16B chunks t and t+512 of each 128-row half
    // (wave-contiguous LDS dest for global_load_lds); global source
    // pre-swizzled so LDS chunk (r, c) holds global k-chunk c ^ (r&7).
    const int ci0 = tid,       r0s = ci0 >> 3, c0s = (ci0 & 7) ^ (r0s & 7);
    const int ci1 = tid + 512, r1s = ci1 >> 3, c1s = (ci1 & 7) ^ (r1s & 7);
    const char* aS0 = qx + (size_t)(bm * 256 + r0s) * K_DIM + c0s * 16;
    const char* aS1 = qx + (size_t)(bm * 256 + r1s) * K_DIM + c1s * 16;
    const char* bS0 = qw + (size_t)(bn * 256 + r0s) * K_DIM + c0s * 16;
    const char* bS1 = qw + (size_t)(bn * 256 + r1s) * K_DIM + c1s * 16;
    const int ldsC0 = ci0 * 16, ldsC1 = ci1 * 16;

#define SLOT_A(par, h) ((par) * 65536 + (h) * 16384)
#define SLOT_B(par, h) ((par) * 65536 + 32768 + (h) * 16384)
#define STAGE_A(par, h, t) do {                                              \
    cp16(lds + SLOT_A(par, h) + ldsC0,                                       \
         aS0 + (size_t)(h) * 128 * K_DIM + (size_t)(t) * 128);               \
    cp16(lds + SLOT_A(par, h) + ldsC1,                                       \
         aS1 + (size_t)(h) * 128 * K_DIM + (size_t)(t) * 128); } while (0)
#define STAGE_B(par, h, t) do {                                              \
    cp16(lds + SLOT_B(par, h) + ldsC0,                                       \
         bS0 + (size_t)(h) * 128 * K_DIM + (size_t)(t) * 128);               \
    cp16(lds + SLOT_B(par, h) + ldsC1,                                       \
         bS1 + (size_t)(h) * 128 * K_DIM + (size_t)(t) * 128); } while (0)

#define BAR()   __builtin_amdgcn_s_barrier()
#define FENCE() asm volatile("" ::: "memory")

    // fragment read offsets (within parity region)
    const int ch0 = (lg ^ (ln & 7)) * 16;   // k-step 0 swizzled chunk byte
    const int ch1 = ch0 ^ 64;               // k-step 1 (chunk index ^ 4)
    const int aRd = wm * 16384 + ln * 128;              // + mt*2048
    const int bRd = 32768 + wn * 8192 + ln * 128;       // + nt*2048

    v4i acc[8][4] = {};

    // ---- prologue: stage tile 0 fully, drain, barrier
    STAGE_A(0, 0, 0); STAGE_A(0, 1, 0);
    STAGE_B(0, 0, 0); STAGE_B(0, 1, 0);
    asm volatile("s_waitcnt vmcnt(0)" ::: "memory");
    BAR(); FENCE();

    for (int t = 0; t < NT; ++t) {
        const int par  = t & 1;
        const int base = par << 16;
        v4i afr[8], bfr[4];

        // ===== P1: k-step 0 — 12 ds_read; stage A(t+1); 32 MFMA ===========
#pragma unroll
        for (int m = 0; m < 8; ++m)
            afr[m] = *(const v4i*)(lds + base + aRd + m * 2048 + ch0);
#pragma unroll
        for (int n = 0; n < 4; ++n)
            bfr[n] = *(const v4i*)(lds + base + bRd + n * 2048 + ch0);
        if (t + 1 < NT) { STAGE_A(par ^ 1, 0, t + 1); STAGE_A(par ^ 1, 1, t + 1); }
        BAR(); FENCE();
        __builtin_amdgcn_s_setprio(1);
#pragma unroll
        for (int m = 0; m < 8; ++m)
#pragma unroll
            for (int n = 0; n < 4; ++n)
                acc[m][n] = __builtin_amdgcn_mfma_i32_16x16x64_i8(
                    afr[m], bfr[n], acc[m][n], 0, 0, 0);
        __builtin_amdgcn_s_setprio(0);
        BAR(); FENCE();

        // ===== P2: k-step 1 — 12 ds_read; stage B(t+1); 32 MFMA;
        //           vmcnt(0) + barrier closes the tile ======================
#pragma unroll
        for (int m = 0; m < 8; ++m)
            afr[m] = *(const v4i*)(lds + base + aRd + m * 2048 + ch1);
#pragma unroll
        for (int n = 0; n < 4; ++n)
            bfr[n] = *(const v4i*)(lds + base + bRd + n * 2048 + ch1);
        if (t + 1 < NT) { STAGE_B(par ^ 1, 0, t + 1); STAGE_B(par ^ 1, 1, t + 1); }
        BAR(); FENCE();
        __builtin_amdgcn_s_setprio(1);
#pragma unroll
        for (int m = 0; m < 8; ++m)
#pragma unroll
            for (int n = 0; n < 4; ++n)
                acc[m][n] = __builtin_amdgcn_mfma_i32_16x16x64_i8(
                    afr[m], bfr[n], acc[m][n], 0, 0, 0);
        __builtin_amdgcn_s_setprio(0);
        asm volatile("s_waitcnt vmcnt(0)" ::: "memory");
        BAR(); FENCE();
    }

    // ---- epilogue (proven). C/D (16x16): col = lane&15, row = lg*4 + reg.
    const int m_base = bm * 256 + wm * 128;
    const int n_base = bn * 256 + wn * 64;

    float sxr[8][4];
#pragma unroll
    for (int m = 0; m < 8; ++m)
#pragma unroll
        for (int r = 0; r < 4; ++r)
            sxr[m][r] = sx[m_base + m * 16 + lg * 4 + r];

#pragma unroll
    for (int n = 0; n < 4; ++n) {
        const int col = n_base + n * 16 + ln;
        const float swv = sw[col];
        const float bv  = bias[col];
#pragma unroll
        for (int m = 0; m < 8; ++m) {
            const int row = m_base + m * 16 + lg * 4;
#pragma unroll
            for (int r = 0; r < 4; ++r) {
                y[(size_t)(row + r) * N_DIM + col] =
                    (float)acc[m][n][r] * sxr[m][r] * swv + bv;
            }
        }
    }
#undef SLOT_A
#undef SLOT_B
#undef STAGE_A
#undef STAGE_B
#undef BAR
#undef FENCE
}

extern "C" void kernel_launch(void* const* d_in, const int* in_sizes, int n_in,
                              void* d_out, int out_size, void* d_ws, size_t ws_size,
                              hipStream_t stream) {
    const float* x = (const float*)d_in[0];   // [B*S, 4096] = [8192, 4096]
    const float* w = (const float*)d_in[1];   // [4096, 4096]
    const float* b = (const float*)d_in[2];   // [4096]
    float* y = (float*)d_out;                 // [8192, 4096]

    const int M = in_sizes[0] / K_DIM;        // 8192
    const int O = in_sizes[1] / K_DIM;        // 4096

    // Workspace layout
    char* qx = (char*)d_ws;                           // M*4096 int8
    char* qw = qx + (size_t)M * K_DIM;                // O*4096 int8
    float* sx = (float*)(qw + (size_t)O * K_DIM);     // M floats
    float* sw = sx + M;                               // O floats

    quant_rows_kernel<<<M + O, 256, 0, stream>>>(x, w, M, qx, qw, sx, sw);

    dim3 grid(N_DIM / 256, M / 256);                  // (16, 32) = 512 blocks
    gemm_i8_kernel<<<grid, 512, 0, stream>>>(qx, qw, sx, sw, b, y);
}